// Round 1
// baseline (542.275 us; speedup 1.0000x reference)
//
#include <hip/hip_runtime.h>
#include <stdint.h>
#include <stddef.h>

#define Hdim 1024
#define Idim 2816
#define Edim 8
#define Tdim 2048

typedef short bf16x8 __attribute__((ext_vector_type(8)));
typedef float f32x4 __attribute__((ext_vector_type(4)));

// ws layout (bytes):
//   0      : cnt[8]   (int)
//   64     : offs[8]  (int)
//   1024   : tok_slot[E*T] int    (65536)
//   66560  : w_slot [E*T] float   (65536)
//   132096 : xbf [T*H] bf16       (4 MiB)
//   4326400: hbuf [2T * I] bf16   (~22 MiB)
#define WS_CNT   0
#define WS_OFFS  64
#define WS_TOK   1024
#define WS_W     66560
#define WS_XBF   132096
#define WS_H     4326400

__device__ __forceinline__ unsigned short f2bf(float f) {
  unsigned int u = __builtin_bit_cast(unsigned int, f);
  u += 0x7fffu + ((u >> 16) & 1u);          // RNE
  return (unsigned short)(u >> 16);
}

__device__ __forceinline__ void async16(const void* g, void* l) {
  __builtin_amdgcn_global_load_lds(
      (const __attribute__((address_space(1))) void*)g,
      (__attribute__((address_space(3))) void*)l, 16, 0, 0);
}

// ---------------- router: logits, softmax, top-2, lists; x -> bf16 ------------
__global__ __launch_bounds__(256) void router_kernel(
    const float* __restrict__ x, const float* __restrict__ rw,
    int* __restrict__ cnt, int* __restrict__ tok_slot,
    float* __restrict__ w_slot, unsigned short* __restrict__ xbf)
{
  const int wave = threadIdx.x >> 6;
  const int lane = threadIdx.x & 63;
  const int t = blockIdx.x * 4 + wave;            // grid 512 -> t < 2048

  float acc[Edim];
#pragma unroll
  for (int e = 0; e < Edim; ++e) acc[e] = 0.f;
  const float* xr = x + (size_t)t * Hdim;
#pragma unroll
  for (int i = 0; i < Hdim / 64; ++i) {
    int idx = i * 64 + lane;
    float v = xr[idx];
    xbf[(size_t)t * Hdim + idx] = f2bf(v);
#pragma unroll
    for (int e = 0; e < Edim; ++e) acc[e] = fmaf(v, rw[e * Hdim + idx], acc[e]);
  }
#pragma unroll
  for (int e = 0; e < Edim; ++e) {
    float a = acc[e];
#pragma unroll
    for (int s = 32; s >= 1; s >>= 1) a += __shfl_xor(a, s, 64);
    acc[e] = a;
  }
  if (lane == 0) {
    float mx = acc[0];
#pragma unroll
    for (int e = 1; e < Edim; ++e) mx = fmaxf(mx, acc[e]);
    float p[Edim], se = 0.f;
#pragma unroll
    for (int e = 0; e < Edim; ++e) { p[e] = __expf(acc[e] - mx); se += p[e]; }
    float inv = 1.f / se;
#pragma unroll
    for (int e = 0; e < Edim; ++e) p[e] *= inv;
    int e1 = 0; float p1 = p[0];
#pragma unroll
    for (int e = 1; e < Edim; ++e) if (p[e] > p1) { p1 = p[e]; e1 = e; }
    int e2 = -1; float p2 = -1.f;
#pragma unroll
    for (int e = 0; e < Edim; ++e) if (e != e1 && p[e] > p2) { p2 = p[e]; e2 = e; }
    int pos1 = atomicAdd(&cnt[e1], 1);
    tok_slot[e1 * Tdim + pos1] = t; w_slot[e1 * Tdim + pos1] = p1;
    int pos2 = atomicAdd(&cnt[e2], 1);
    tok_slot[e2 * Tdim + pos2] = t; w_slot[e2 * Tdim + pos2] = p2;
  }
}

// ---------------- prefix offsets over 8 experts -------------------------------
__global__ void offs_kernel(const int* __restrict__ cnt, int* __restrict__ offs)
{
  if (threadIdx.x == 0 && blockIdx.x == 0) {
    int s = 0;
    for (int e = 0; e < Edim; ++e) { offs[e] = s; s += cnt[e]; }
  }
}

// ---------------- gate+up grouped GEMM + silu -> h (bf16) ---------------------
// grid: (I/64 = 44, T/128 = 16, E = 8), 256 threads
__global__ __launch_bounds__(256) void gateup_kernel(
    const unsigned short* __restrict__ xbf,
    const float* __restrict__ gw, const float* __restrict__ uw,
    const int* __restrict__ cnt, const int* __restrict__ offs,
    const int* __restrict__ tok_slot, unsigned short* __restrict__ hbuf)
{
  const int e = blockIdx.z, mtile = blockIdx.y, ntile = blockIdx.x;
  const int n_e = cnt[e];
  if (mtile * 128 >= n_e) return;

  __shared__ unsigned short Al[2][128][32];
  __shared__ unsigned short Bgl[2][64][32];
  __shared__ unsigned short Bul[2][64][32];
  __shared__ int toks[128];

  const int tid = threadIdx.x;
  const int wave = tid >> 6, lane = tid & 63;
  const int wr = (wave >> 1) * 64, wc = (wave & 1) * 32;

  if (tid < 128) {
    int r = mtile * 128 + tid;
    toks[tid] = tok_slot[e * Tdim + ((r < n_e) ? r : mtile * 128)];
  }
  __syncthreads();

  const int br = tid >> 2, bc = tid & 3;   // B staging: row 0..63, chunk 0..3
  const float* gbase = gw + ((size_t)e * Idim + (size_t)ntile * 64 + br) * Hdim + bc * 8;
  const float* ubase = uw + ((size_t)e * Idim + (size_t)ntile * 64 + br) * Hdim + bc * 8;

  f32x4 accg[4][2], accu[4][2];
#pragma unroll
  for (int m = 0; m < 4; ++m)
#pragma unroll
    for (int n = 0; n < 2; ++n) {
      f32x4 z = {0.f, 0.f, 0.f, 0.f};
      accg[m][n] = z; accu[m][n] = z;
    }

  f32x4 bg0, bg1, bu0, bu1;
  auto loadB = [&](int kt) {
    const float* gp = gbase + (size_t)kt * 32;
    const float* up = ubase + (size_t)kt * 32;
    bg0 = *(const f32x4*)gp; bg1 = *(const f32x4*)(gp + 4);
    bu0 = *(const f32x4*)up; bu1 = *(const f32x4*)(up + 4);
  };
  auto writeB = [&](int buf) {
    bf16x8 vg, vu;
#pragma unroll
    for (int j = 0; j < 4; ++j) {
      vg[j] = (short)f2bf(bg0[j]); vg[j + 4] = (short)f2bf(bg1[j]);
      vu[j] = (short)f2bf(bu0[j]); vu[j + 4] = (short)f2bf(bu1[j]);
    }
    *(bf16x8*)&Bgl[buf][br][bc * 8] = vg;
    *(bf16x8*)&Bul[buf][br][bc * 8] = vu;
  };
  auto stageA = [&](int buf, int kt) {
#pragma unroll
    for (int ii = 0; ii < 2; ++ii) {
      int i = wave + ii * 4;                       // 0..7, 16 rows each
      int row = i * 16 + (lane >> 2);
      int t = toks[row];
      const unsigned short* g = xbf + (size_t)t * Hdim + kt * 32 + (lane & 3) * 8;
      async16(g, &Al[buf][i * 16][0]);             // dest = base + lane*16
    }
  };
  auto compute = [&](int buf) {
    bf16x8 af[4], bgf[2], buff[2];
#pragma unroll
    for (int m = 0; m < 4; ++m)
      af[m] = *(const bf16x8*)&Al[buf][wr + m * 16 + (lane & 15)][(lane >> 4) * 8];
#pragma unroll
    for (int n = 0; n < 2; ++n) {
      bgf[n] = *(const bf16x8*)&Bgl[buf][wc + n * 16 + (lane & 15)][(lane >> 4) * 8];
      buff[n] = *(const bf16x8*)&Bul[buf][wc + n * 16 + (lane & 15)][(lane >> 4) * 8];
    }
#pragma unroll
    for (int m = 0; m < 4; ++m)
#pragma unroll
      for (int n = 0; n < 2; ++n) {
        accg[m][n] = __builtin_amdgcn_mfma_f32_16x16x32_bf16(af[m], bgf[n], accg[m][n], 0, 0, 0);
        accu[m][n] = __builtin_amdgcn_mfma_f32_16x16x32_bf16(af[m], buff[n], accu[m][n], 0, 0, 0);
      }
  };

  loadB(0); stageA(0, 0); writeB(0);
  __syncthreads();
  int cur = 0;
  for (int kt = 0; kt < Hdim / 32 - 1; ++kt) {
    loadB(kt + 1);
    stageA(cur ^ 1, kt + 1);
    compute(cur);
    writeB(cur ^ 1);
    __syncthreads();
    cur ^= 1;
  }
  compute(cur);

  const size_t hb = (size_t)offs[e];
#pragma unroll
  for (int m = 0; m < 4; ++m)
#pragma unroll
    for (int n = 0; n < 2; ++n)
#pragma unroll
      for (int j = 0; j < 4; ++j) {
        int r = wr + m * 16 + ((lane >> 4) << 2) + j;
        int gr = mtile * 128 + r;
        if (gr < n_e) {
          int col = ntile * 64 + wc + n * 16 + (lane & 15);
          float g = accg[m][n][j], u = accu[m][n][j];
          float s = g / (1.f + __expf(-g));        // silu(g)
          hbuf[(hb + (size_t)gr) * Idim + col] = f2bf(s * u);
        }
      }
}

// ---------------- down grouped GEMM, scale by w_te, atomicAdd -----------------
// grid: (H/64 = 16, T/128 = 16, E = 8), 256 threads
__global__ __launch_bounds__(256) void down_kernel(
    const unsigned short* __restrict__ hbuf, const float* __restrict__ dw,
    const int* __restrict__ cnt, const int* __restrict__ offs,
    const int* __restrict__ tok_slot, const float* __restrict__ w_slot,
    float* __restrict__ out)
{
  const int e = blockIdx.z, mtile = blockIdx.y, ntile = blockIdx.x;
  const int n_e = cnt[e];
  if (mtile * 128 >= n_e) return;
  const int off_e = offs[e];

  __shared__ unsigned short Al[2][128][32];
  __shared__ unsigned short Bl[2][64][32];
  __shared__ int toks[128];
  __shared__ float wts[128];

  const int tid = threadIdx.x;
  const int wave = tid >> 6, lane = tid & 63;
  const int wr = (wave >> 1) * 64, wc = (wave & 1) * 32;

  if (tid < 128) {
    int r = mtile * 128 + tid;
    int rc = (r < n_e) ? r : mtile * 128;
    toks[tid] = tok_slot[e * Tdim + rc];
    wts[tid]  = w_slot[e * Tdim + rc];
  }
  __syncthreads();

  const int br = tid >> 2, bc = tid & 3;
  const float* dbase = dw + ((size_t)e * Hdim + (size_t)ntile * 64 + br) * Idim + bc * 8;

  f32x4 acc[4][2];
#pragma unroll
  for (int m = 0; m < 4; ++m)
#pragma unroll
    for (int n = 0; n < 2; ++n) { f32x4 z = {0.f, 0.f, 0.f, 0.f}; acc[m][n] = z; }

  f32x4 b0, b1;
  auto loadB = [&](int kt) {
    const float* p = dbase + (size_t)kt * 32;
    b0 = *(const f32x4*)p; b1 = *(const f32x4*)(p + 4);
  };
  auto writeB = [&](int buf) {
    bf16x8 v;
#pragma unroll
    for (int j = 0; j < 4; ++j) { v[j] = (short)f2bf(b0[j]); v[j + 4] = (short)f2bf(b1[j]); }
    *(bf16x8*)&Bl[buf][br][bc * 8] = v;
  };
  auto stageA = [&](int buf, int kt) {
#pragma unroll
    for (int ii = 0; ii < 2; ++ii) {
      int i = wave + ii * 4;
      int row = i * 16 + (lane >> 2);
      int gr = mtile * 128 + row;
      int grc = (gr < n_e) ? gr : mtile * 128;
      const unsigned short* g = hbuf + (size_t)(off_e + grc) * Idim + kt * 32 + (lane & 3) * 8;
      async16(g, &Al[buf][i * 16][0]);
    }
  };
  auto compute = [&](int buf) {
    bf16x8 af[4], bf[2];
#pragma unroll
    for (int m = 0; m < 4; ++m)
      af[m] = *(const bf16x8*)&Al[buf][wr + m * 16 + (lane & 15)][(lane >> 4) * 8];
#pragma unroll
    for (int n = 0; n < 2; ++n)
      bf[n] = *(const bf16x8*)&Bl[buf][wc + n * 16 + (lane & 15)][(lane >> 4) * 8];
#pragma unroll
    for (int m = 0; m < 4; ++m)
#pragma unroll
      for (int n = 0; n < 2; ++n)
        acc[m][n] = __builtin_amdgcn_mfma_f32_16x16x32_bf16(af[m], bf[n], acc[m][n], 0, 0, 0);
  };

  loadB(0); stageA(0, 0); writeB(0);
  __syncthreads();
  int cur = 0;
  for (int kt = 0; kt < Idim / 32 - 1; ++kt) {
    loadB(kt + 1);
    stageA(cur ^ 1, kt + 1);
    compute(cur);
    writeB(cur ^ 1);
    __syncthreads();
    cur ^= 1;
  }
  compute(cur);

#pragma unroll
  for (int m = 0; m < 4; ++m)
#pragma unroll
    for (int n = 0; n < 2; ++n)
#pragma unroll
      for (int j = 0; j < 4; ++j) {
        int r = wr + m * 16 + ((lane >> 4) << 2) + j;
        int gr = mtile * 128 + r;
        if (gr < n_e) {
          int col = ntile * 64 + wc + n * 16 + (lane & 15);
          float v = acc[m][n][j] * wts[r];
          atomicAdd(out + (size_t)toks[r] * Hdim + col, v);
        }
      }
}

extern "C" void kernel_launch(void* const* d_in, const int* in_sizes, int n_in,
                              void* d_out, int out_size, void* d_ws, size_t ws_size,
                              hipStream_t stream) {
  const float* x  = (const float*)d_in[0];
  const float* rw = (const float*)d_in[1];
  const float* gw = (const float*)d_in[2];
  const float* uw = (const float*)d_in[3];
  const float* dw = (const float*)d_in[4];
  float* out = (float*)d_out;

  char* ws = (char*)d_ws;
  int*   cnt  = (int*)(ws + WS_CNT);
  int*   offs = (int*)(ws + WS_OFFS);
  int*   tok  = (int*)(ws + WS_TOK);
  float* wsl  = (float*)(ws + WS_W);
  unsigned short* xbf  = (unsigned short*)(ws + WS_XBF);
  unsigned short* hbuf = (unsigned short*)(ws + WS_H);

  hipMemsetAsync(cnt, 0, 64, stream);
  hipMemsetAsync(out, 0, (size_t)out_size * sizeof(float), stream);

  router_kernel<<<Tdim / 4, 256, 0, stream>>>(x, rw, cnt, tok, wsl, xbf);
  offs_kernel<<<1, 64, 0, stream>>>(cnt, offs);
  gateup_kernel<<<dim3(Idim / 64, Tdim / 128, Edim), 256, 0, stream>>>(
      xbf, gw, uw, cnt, offs, tok, hbuf);
  down_kernel<<<dim3(Hdim / 64, Tdim / 128, Edim), 256, 0, stream>>>(
      hbuf, dw, cnt, offs, tok, wsl, out);
}

// Round 4
// 497.725 us; speedup vs baseline: 1.0895x; 1.0895x over previous
//
#include <hip/hip_runtime.h>
#include <stdint.h>
#include <stddef.h>

#define Hdim 1024
#define Idim 2816
#define Edim 8
#define Tdim 2048

typedef short bf16x8 __attribute__((ext_vector_type(8)));
typedef float f32x4 __attribute__((ext_vector_type(4)));
typedef unsigned short us4 __attribute__((ext_vector_type(4)));

// ws layout (bytes)
#define WS_CNT   0
#define WS_OFFS  64
#define WS_TOK   1024       // int[E*T]
#define WS_W     66560      // float[E*T]
#define WS_MAP   132096     // int[2*T]
#define WS_XBF   148480     // bf16[T*H]       (4 MiB)
#define WS_H     4342784    // bf16[2T*I]      (22 MiB)
#define WS_Y     27411456   // bf16[2T*H]      (8 MiB)   -> ends ~35.8 MiB

__device__ __forceinline__ unsigned short f2bf(float f) {
  unsigned int u = __builtin_bit_cast(unsigned int, f);
  u += 0x7fffu + ((u >> 16) & 1u);          // RNE
  return (unsigned short)(u >> 16);
}
__device__ __forceinline__ float bf2f(unsigned short h) {
  unsigned int u = ((unsigned int)h) << 16;
  return __builtin_bit_cast(float, u);
}
__device__ __forceinline__ void async16(const void* g, void* l) {
  __builtin_amdgcn_global_load_lds(
      (const __attribute__((address_space(1))) void*)g,
      (__attribute__((address_space(3))) void*)l, 16, 0, 0);
}

// ---------------- router: logits, softmax, top-2, lists; x -> bf16 ------------
__global__ __launch_bounds__(256) void router_kernel(
    const float* __restrict__ x, const float* __restrict__ rw,
    int* __restrict__ cnt, int* __restrict__ tok_slot,
    float* __restrict__ w_slot, int* __restrict__ tokmap,
    unsigned short* __restrict__ xbf)
{
  const int wave = threadIdx.x >> 6;
  const int lane = threadIdx.x & 63;
  const int t = blockIdx.x * 4 + wave;            // grid 512 -> t < 2048

  float acc[Edim];
#pragma unroll
  for (int e = 0; e < Edim; ++e) acc[e] = 0.f;
  const float* xr = x + (size_t)t * Hdim;
#pragma unroll
  for (int i = 0; i < Hdim / 64; ++i) {
    int idx = i * 64 + lane;
    float v = xr[idx];
    xbf[(size_t)t * Hdim + idx] = f2bf(v);
#pragma unroll
    for (int e = 0; e < Edim; ++e) acc[e] = fmaf(v, rw[e * Hdim + idx], acc[e]);
  }
#pragma unroll
  for (int e = 0; e < Edim; ++e) {
    float a = acc[e];
#pragma unroll
    for (int s = 32; s >= 1; s >>= 1) a += __shfl_xor(a, s, 64);
    acc[e] = a;
  }
  if (lane == 0) {
    float mx = acc[0];
#pragma unroll
    for (int e = 1; e < Edim; ++e) mx = fmaxf(mx, acc[e]);
    float p[Edim], se = 0.f;
#pragma unroll
    for (int e = 0; e < Edim; ++e) { p[e] = __expf(acc[e] - mx); se += p[e]; }
    float inv = 1.f / se;
#pragma unroll
    for (int e = 0; e < Edim; ++e) p[e] *= inv;
    int e1 = 0; float p1 = p[0];
#pragma unroll
    for (int e = 1; e < Edim; ++e) if (p[e] > p1) { p1 = p[e]; e1 = e; }
    int e2 = -1; float p2 = -1.f;
#pragma unroll
    for (int e = 0; e < Edim; ++e) if (e != e1 && p[e] > p2) { p2 = p[e]; e2 = e; }
    int pos1 = atomicAdd(&cnt[e1], 1);
    tok_slot[e1 * Tdim + pos1] = t; w_slot[e1 * Tdim + pos1] = p1;
    tokmap[t] = e1 * Tdim + pos1;
    int pos2 = atomicAdd(&cnt[e2], 1);
    tok_slot[e2 * Tdim + pos2] = t; w_slot[e2 * Tdim + pos2] = p2;
    tokmap[Tdim + t] = e2 * Tdim + pos2;
  }
}

// ---------------- prefix offsets over 8 experts -------------------------------
__global__ void offs_kernel(const int* __restrict__ cnt, int* __restrict__ offs)
{
  if (threadIdx.x == 0 && blockIdx.x == 0) {
    int s = 0;
    for (int e = 0; e < Edim; ++e) { offs[e] = s; s += cnt[e]; }
  }
}

// ---------------- gate+up grouped GEMM + silu -> h (bf16) ---------------------
// grid: (I/64 = 44, T/128 = 16, E = 8), 256 threads.  BK = 32.
// LDS in MFMA-fragment order: group = subtile-of-16, then [lane][16B].
__global__ __launch_bounds__(256) void gateup_kernel(
    const unsigned short* __restrict__ xbf,
    const float* __restrict__ gw, const float* __restrict__ uw,
    const int* __restrict__ cnt, const int* __restrict__ offs,
    const int* __restrict__ tok_slot, unsigned short* __restrict__ hbuf)
{
  const int e = blockIdx.z, mtile = blockIdx.y, ntile = blockIdx.x;
  const int n_e = cnt[e];
  if (mtile * 128 >= n_e) return;

  __shared__ unsigned short A [2][8][64][8];   // 16 KB (mb groups 0..7)
  __shared__ unsigned short Bg[2][4][64][8];   // 8 KB  (nb groups 0..3)
  __shared__ unsigned short Bu[2][4][64][8];   // 8 KB
  __shared__ int toks[128];

  const int tid = threadIdx.x;
  const int wave = tid >> 6, lane = tid & 63;
  const int wr = (wave >> 1) * 64, wc = (wave & 1) * 32;
  const int wr16 = (wave >> 1) * 4, wc16 = (wave & 1) * 2;

  if (tid < 128) {
    int r = mtile * 128 + tid;
    toks[tid] = tok_slot[e * Tdim + ((r < n_e) ? r : (n_e - 1))];
  }
  __syncthreads();

  // B staging: thread -> row br (0..63), k-chunk bc*8 (8 floats)
  const int br = tid >> 2, bc = tid & 3;
  const float* gbase = gw + ((size_t)e * Idim + (size_t)ntile * 64 + br) * Hdim + bc * 8;
  const float* ubase = uw + ((size_t)e * Idim + (size_t)ntile * 64 + br) * Hdim + bc * 8;
  const int bslot = bc * 16 + (br & 15);       // fragment lane slot
  const int bgrp  = br >> 4;                   // nb group

  f32x4 accg[4][2], accu[4][2];
#pragma unroll
  for (int m = 0; m < 4; ++m)
#pragma unroll
    for (int n = 0; n < 2; ++n) {
      f32x4 z = {0.f, 0.f, 0.f, 0.f};
      accg[m][n] = z; accu[m][n] = z;
    }

  f32x4 bg0, bg1, bu0, bu1;
  auto loadB = [&](int kt) {
    const float* gp = gbase + (size_t)kt * 32;
    const float* up = ubase + (size_t)kt * 32;
    bg0 = *(const f32x4*)gp; bg1 = *(const f32x4*)(gp + 4);
    bu0 = *(const f32x4*)up; bu1 = *(const f32x4*)(up + 4);
  };
  auto writeB = [&](int buf) {
    bf16x8 vg, vu;
#pragma unroll
    for (int j = 0; j < 4; ++j) {
      vg[j] = (short)f2bf(bg0[j]); vg[j + 4] = (short)f2bf(bg1[j]);
      vu[j] = (short)f2bf(bu0[j]); vu[j + 4] = (short)f2bf(bu1[j]);
    }
    *(bf16x8*)&Bg[buf][bgrp][bslot][0] = vg;
    *(bf16x8*)&Bu[buf][bgrp][bslot][0] = vu;
  };
  // A staging, fragment order: lane l of group mb holds row mb*16+(l&15), k-chunk (l>>4)*8
  auto stageA = [&](int buf, int kt) {
#pragma unroll
    for (int ii = 0; ii < 2; ++ii) {
      int mb = wave + ii * 4;
      int t = toks[mb * 16 + (lane & 15)];
      const unsigned short* g = xbf + (size_t)t * Hdim + kt * 32 + (lane >> 4) * 8;
      async16(g, &A[buf][mb][0][0]);
    }
  };
  auto compute = [&](int buf) {
    bf16x8 af[4], bgf[2], buf_[2];
#pragma unroll
    for (int m = 0; m < 4; ++m)
      af[m] = *(const bf16x8*)&A[buf][wr16 + m][lane][0];
#pragma unroll
    for (int n = 0; n < 2; ++n) {
      bgf[n] = *(const bf16x8*)&Bg[buf][wc16 + n][lane][0];
      buf_[n] = *(const bf16x8*)&Bu[buf][wc16 + n][lane][0];
    }
#pragma unroll
    for (int m = 0; m < 4; ++m)
#pragma unroll
      for (int n = 0; n < 2; ++n) {
        accg[m][n] = __builtin_amdgcn_mfma_f32_16x16x32_bf16(af[m], bgf[n], accg[m][n], 0, 0, 0);
        accu[m][n] = __builtin_amdgcn_mfma_f32_16x16x32_bf16(af[m], buf_[n], accu[m][n], 0, 0, 0);
      }
  };

  loadB(0); stageA(0, 0); writeB(0);
  __syncthreads();
  int cur = 0;
  for (int kt = 0; kt < Hdim / 32 - 1; ++kt) {
    loadB(kt + 1);
    stageA(cur ^ 1, kt + 1);
    compute(cur);
    writeB(cur ^ 1);
    __syncthreads();
    cur ^= 1;
  }
  compute(cur);

  const size_t hb = (size_t)offs[e];
#pragma unroll
  for (int m = 0; m < 4; ++m)
#pragma unroll
    for (int n = 0; n < 2; ++n)
#pragma unroll
      for (int j = 0; j < 4; ++j) {
        int r = wr + m * 16 + ((lane >> 4) << 2) + j;
        int gr = mtile * 128 + r;
        if (gr < n_e) {
          int col = ntile * 64 + wc + n * 16 + (lane & 15);
          float g = accg[m][n][j], u = accu[m][n][j];
          float s = g / (1.f + __expf(-g));        // silu(g)
          hbuf[(hb + (size_t)gr) * Idim + col] = f2bf(s * u);
        }
      }
}

// ---------------- down grouped GEMM -> ybuf (bf16, slot-major, no atomics) ----
// grid: (H/64 = 16, T/128 = 16, E = 8), 256 threads.  BK = 64.
__global__ __launch_bounds__(256) void down_kernel(
    const unsigned short* __restrict__ hbuf, const float* __restrict__ dw,
    const int* __restrict__ cnt, const int* __restrict__ offs,
    unsigned short* __restrict__ ybuf)
{
  const int e = blockIdx.z, mtile = blockIdx.y, ntile = blockIdx.x;
  const int n_e = cnt[e];
  if (mtile * 128 >= n_e) return;
  const int off_e = offs[e];

  __shared__ unsigned short A [2][16][64][8];  // 32 KB (group = mb*2+kc)
  __shared__ unsigned short Bl[2][8][64][8];   // 16 KB (group = nb*2+kc)

  const int tid = threadIdx.x;
  const int wave = tid >> 6, lane = tid & 63;
  const int wr = (wave >> 1) * 64, wc = (wave & 1) * 32;
  const int wr16 = (wave >> 1) * 4, wc2 = (wave & 1) * 2;

  // B staging: thread -> row br (0..63), 16 consecutive floats at k = kq*16
  const int br = tid >> 2, kq = tid & 3;
  const float* dbase = dw + ((size_t)e * Hdim + (size_t)ntile * 64 + br) * Idim + kq * 16;
  const int k0 = kq * 16;
  const int g0 = (br >> 4) * 2 + (k0 >> 5);
  const int l0 = (((k0 & 31) >> 3) << 4) + (br & 15);
  const int k1 = k0 + 8;
  const int g1 = (br >> 4) * 2 + (k1 >> 5);
  const int l1 = (((k1 & 31) >> 3) << 4) + (br & 15);

  f32x4 acc[4][2];
#pragma unroll
  for (int m = 0; m < 4; ++m)
#pragma unroll
    for (int n = 0; n < 2; ++n) { f32x4 z = {0.f, 0.f, 0.f, 0.f}; acc[m][n] = z; }

  f32x4 b0, b1, b2, b3;
  auto loadB = [&](int kt) {
    const float* p = dbase + (size_t)kt * 64;
    b0 = *(const f32x4*)p;        b1 = *(const f32x4*)(p + 4);
    b2 = *(const f32x4*)(p + 8);  b3 = *(const f32x4*)(p + 12);
  };
  auto writeB = [&](int buf) {
    bf16x8 v0, v1;
#pragma unroll
    for (int j = 0; j < 4; ++j) {
      v0[j] = (short)f2bf(b0[j]); v0[j + 4] = (short)f2bf(b1[j]);
      v1[j] = (short)f2bf(b2[j]); v1[j + 4] = (short)f2bf(b3[j]);
    }
    *(bf16x8*)&Bl[buf][g0][l0][0] = v0;
    *(bf16x8*)&Bl[buf][g1][l1][0] = v1;
  };
  auto stageA = [&](int buf, int kt) {
#pragma unroll
    for (int ii = 0; ii < 2; ++ii) {
      int mb = wave + ii * 4;
      int gr = mtile * 128 + mb * 16 + (lane & 15);
      int rc = (gr < n_e) ? gr : (n_e - 1);
#pragma unroll
      for (int kc = 0; kc < 2; ++kc) {
        const unsigned short* g = hbuf + (size_t)(off_e + rc) * Idim
                                + (size_t)kt * 64 + kc * 32 + (lane >> 4) * 8;
        async16(g, &A[buf][mb * 2 + kc][0][0]);
      }
    }
  };
  auto compute = [&](int buf) {
    bf16x8 af[4][2], bfr[2][2];
#pragma unroll
    for (int m = 0; m < 4; ++m)
#pragma unroll
      for (int kk = 0; kk < 2; ++kk)
        af[m][kk] = *(const bf16x8*)&A[buf][(wr16 + m) * 2 + kk][lane][0];
#pragma unroll
    for (int n = 0; n < 2; ++n)
#pragma unroll
      for (int kk = 0; kk < 2; ++kk)
        bfr[n][kk] = *(const bf16x8*)&Bl[buf][(wc2 + n) * 2 + kk][lane][0];
#pragma unroll
    for (int m = 0; m < 4; ++m)
#pragma unroll
      for (int n = 0; n < 2; ++n)
#pragma unroll
        for (int kk = 0; kk < 2; ++kk)
          acc[m][n] = __builtin_amdgcn_mfma_f32_16x16x32_bf16(af[m][kk], bfr[n][kk], acc[m][n], 0, 0, 0);
  };

  loadB(0); stageA(0, 0); writeB(0);
  __syncthreads();
  int cur = 0;
  for (int kt = 0; kt < Idim / 64 - 1; ++kt) {
    loadB(kt + 1);
    stageA(cur ^ 1, kt + 1);
    compute(cur);
    writeB(cur ^ 1);
    __syncthreads();
    cur ^= 1;
  }
  compute(cur);

#pragma unroll
  for (int m = 0; m < 4; ++m)
#pragma unroll
    for (int n = 0; n < 2; ++n)
#pragma unroll
      for (int j = 0; j < 4; ++j) {
        int r = wr + m * 16 + ((lane >> 4) << 2) + j;
        int gr = mtile * 128 + r;
        if (gr < n_e) {
          int col = ntile * 64 + wc + n * 16 + (lane & 15);
          ybuf[(size_t)(off_e + gr) * Hdim + col] = f2bf(acc[m][n][j]);
        }
      }
}

// ---------------- combine: out[t] = w1*y[slot1] + w2*y[slot2] -----------------
// grid: (T = 2048), 256 threads, 4 f32 per thread
__global__ __launch_bounds__(256) void combine_kernel(
    const unsigned short* __restrict__ ybuf, const int* __restrict__ offs,
    const int* __restrict__ tokmap, const float* __restrict__ w_slot,
    float* __restrict__ out)
{
  const int t = blockIdx.x;
  const int i1 = tokmap[t], i2 = tokmap[Tdim + t];
  const float w1 = w_slot[i1], w2 = w_slot[i2];
  const int s1 = offs[i1 >> 11] + (i1 & (Tdim - 1));
  const int s2 = offs[i2 >> 11] + (i2 & (Tdim - 1));
  const int c = threadIdx.x * 4;
  us4 a = *(const us4*)&ybuf[(size_t)s1 * Hdim + c];
  us4 b = *(const us4*)&ybuf[(size_t)s2 * Hdim + c];
  f32x4 r;
#pragma unroll
  for (int j = 0; j < 4; ++j) r[j] = w1 * bf2f(a[j]) + w2 * bf2f(b[j]);
  *(f32x4*)&out[(size_t)t * Hdim + c] = r;
}

extern "C" void kernel_launch(void* const* d_in, const int* in_sizes, int n_in,
                              void* d_out, int out_size, void* d_ws, size_t ws_size,
                              hipStream_t stream) {
  const float* x  = (const float*)d_in[0];
  const float* rw = (const float*)d_in[1];
  const float* gw = (const float*)d_in[2];
  const float* uw = (const float*)d_in[3];
  const float* dw = (const float*)d_in[4];
  float* out = (float*)d_out;

  char* ws = (char*)d_ws;
  int*   cnt  = (int*)(ws + WS_CNT);
  int*   offs = (int*)(ws + WS_OFFS);
  int*   tok  = (int*)(ws + WS_TOK);
  float* wsl  = (float*)(ws + WS_W);
  int*   map  = (int*)(ws + WS_MAP);
  unsigned short* xbf  = (unsigned short*)(ws + WS_XBF);
  unsigned short* hbuf = (unsigned short*)(ws + WS_H);
  unsigned short* ybuf = (unsigned short*)(ws + WS_Y);

  hipMemsetAsync(cnt, 0, 64, stream);

  router_kernel<<<Tdim / 4, 256, 0, stream>>>(x, rw, cnt, tok, wsl, map, xbf);
  offs_kernel<<<1, 64, 0, stream>>>(cnt, offs);
  gateup_kernel<<<dim3(Idim / 64, Tdim / 128, Edim), 256, 0, stream>>>(
      xbf, gw, uw, cnt, offs, tok, hbuf);
  down_kernel<<<dim3(Hdim / 64, Tdim / 128, Edim), 256, 0, stream>>>(
      hbuf, dw, cnt, offs, ybuf);
  combine_kernel<<<Tdim, 256, 0, stream>>>(ybuf, offs, map, wsl, out);
}